// Round 1
// baseline (751.531 us; speedup 1.0000x reference)
//
#include <hip/hip_runtime.h>
#include <math.h>

#define Hn 256
#define NHn 4
#define HDn 64
#define DWn 32
#define DAn 32
#define DVn 32
#define DGn 64
#define Bqn 2
#define Qln 8
#define Tln 512
#define EBn 16

__device__ __forceinline__ float sigm(float x) { return 1.0f / (1.0f + expf(-x)); }

__device__ __forceinline__ float wsum64(float v) {
#pragma unroll
    for (int m = 32; m >= 1; m >>= 1) v += __shfl_xor(v, m, 64);
    return v;
}

// ---------------- Kernel A: per (b,t): k, kk (normalized), vraw, sv ----------------
__global__ void kA(const float* __restrict__ keyval,
                   const float* __restrict__ x_k, const float* __restrict__ x_v,
                   const float* __restrict__ Wk, const float* __restrict__ Wv,
                   const float* __restrict__ v0, const float* __restrict__ v1,
                   const float* __restrict__ v2, const float* __restrict__ k_k,
                   float* __restrict__ k_g, float* __restrict__ kk_g,
                   float* __restrict__ vraw_g, float* __restrict__ sv_g) {
    int bt = blockIdx.x;              // b*Tl + t
    int t = bt & (Tln - 1);
    int c = threadIdx.x;              // channel 0..255

    __shared__ __align__(16) float xk_s[Hn];
    __shared__ __align__(16) float xv_s[Hn];
    __shared__ float hv_s[DVn];

    float hs = keyval[bt * Hn + c];
    float pv = (t > 0) ? keyval[(bt - 1) * Hn + c] : 0.0f;
    float d = pv - hs;
    xk_s[c] = fmaf(d, x_k[c], hs);
    xv_s[c] = fmaf(d, x_v[c], hs);
    __syncthreads();

    // hv[d] = xv @ v1, threads 0..31
    if (c < DVn) {
        float acc = 0.f;
#pragma unroll 8
        for (int j = 0; j < Hn; ++j) acc = fmaf(xv_s[j], v1[j * DVn + c], acc);
        hv_s[c] = acc;
    }

    // k and vraw matvecs (row c of Wk/Wv)
    float kacc = 0.f, vacc = 0.f;
    const float4* xk4 = (const float4*)xk_s;
    const float4* xv4 = (const float4*)xv_s;
    const float4* wk4 = (const float4*)(Wk + c * Hn);
    const float4* wv4 = (const float4*)(Wv + c * Hn);
#pragma unroll 8
    for (int j = 0; j < Hn / 4; ++j) {
        float4 xa = xk4[j], wa = wk4[j];
        kacc += xa.x * wa.x + xa.y * wa.y + xa.z * wa.z + xa.w * wa.w;
        float4 xb = xv4[j], wb = wv4[j];
        vacc += xb.x * wb.x + xb.y * wb.y + xb.z * wb.z + xb.w * wb.w;
    }
    __syncthreads();

    // sv = sigmoid(v0 + hv @ v2)
    float svacc = v0[c];
#pragma unroll 8
    for (int dd = 0; dd < DVn; ++dd) svacc = fmaf(hv_s[dd], v2[dd * Hn + c], svacc);
    float sv = sigm(svacc);

    // kk = (k * k_k) normalized per head; head == wave (64 consecutive channels)
    float kkraw = kacc * k_k[c];
    float ss = wsum64(kkraw * kkraw);
    float denom = fmaxf(sqrtf(ss), 1e-12f);
    float kk = kkraw / denom;

    int o = bt * Hn + c;
    k_g[o] = kacc;
    kk_g[o] = kk;
    vraw_g[o] = vacc;
    sv_g[o] = sv;
}

// ---------------- Kernel B: per (eb,t): ew=exp(w), km=k*(1+(a-1)*k_a), ck=kk*a ----
__global__ void kB(const float* __restrict__ query, const float* __restrict__ keyval,
                   const float* __restrict__ x_w, const float* __restrict__ x_a,
                   const float* __restrict__ w0, const float* __restrict__ w1,
                   const float* __restrict__ w2, const float* __restrict__ a0,
                   const float* __restrict__ a1, const float* __restrict__ a2,
                   const float* __restrict__ k_a,
                   const float* __restrict__ k_g, const float* __restrict__ kk_g,
                   float* __restrict__ ew_g, float* __restrict__ km_g,
                   float* __restrict__ ck_g) {
    const float NEGC = -0.60653065971263342f;  // -exp(-0.5)
    int id = blockIdx.x;               // eb*Tl + t
    int eb = id >> 9, t = id & (Tln - 1);
    int b = eb >> 3;                   // eb / Ql
    int c = threadIdx.x;

    __shared__ __align__(16) float xw_s[Hn];
    __shared__ __align__(16) float xa_s[Hn];
    __shared__ float hw_s[DWn];
    __shared__ float ha_s[DAn];

    int bt = (b << 9) + t;
    float hs = keyval[bt * Hn + c];
    float q = query[eb * Hn + c];
    float d = q - hs;
    xw_s[c] = fmaf(d, x_w[c], hs);
    xa_s[c] = fmaf(d, x_a[c], hs);
    __syncthreads();

    if (c < DWn) {
        float acc = 0.f;
#pragma unroll 8
        for (int j = 0; j < Hn; ++j) acc = fmaf(xw_s[j], w1[j * DWn + c], acc);
        hw_s[c] = tanhf(acc);
    } else if (c < DWn + DAn) {
        int dd = c - DWn;
        float acc = 0.f;
#pragma unroll 8
        for (int j = 0; j < Hn; ++j) acc = fmaf(xa_s[j], a1[j * DAn + dd], acc);
        ha_s[dd] = acc;
    }
    __syncthreads();

    float wacc = w0[c], aacc = a0[c];
#pragma unroll 8
    for (int dd = 0; dd < DWn; ++dd) {
        wacc = fmaf(hw_s[dd], w2[dd * Hn + c], wacc);
        aacc = fmaf(ha_s[dd], a2[dd * Hn + c], aacc);
    }
    float w = NEGC * sigm(wacc);
    float a = sigm(aacc);

    int obt = bt * Hn + c;
    int oet = id * Hn + c;
    float kv = k_g[obt];
    float kkv = kk_g[obt];
    ew_g[oet] = expf(w);
    km_g[oet] = kv * fmaf(a - 1.0f, k_a[c], 1.0f);
    ck_g[oet] = kkv * a;
}

// ---------------- Kernel C: the sequential scan. 1 wave per (eb,h). lane = v-col --
__global__ __launch_bounds__(64) void kScan(
    const float* __restrict__ kk_g, const float* __restrict__ ew_g,
    const float* __restrict__ km_g, const float* __restrict__ ck_g,
    const float* __restrict__ vraw_g, const float* __restrict__ sv_g,
    const float* __restrict__ v_first,
    const float* __restrict__ query, const float* __restrict__ keyval,
    const float* __restrict__ x_r, const float* __restrict__ x_g,
    const float* __restrict__ Wr, const float* __restrict__ g1,
    const float* __restrict__ g2, const float* __restrict__ r_k,
    const float* __restrict__ gn_w, const float* __restrict__ gn_b,
    float* __restrict__ o_buf) {
    const float EPSC = 64e-5f;  // HD * 1e-5
    int blk = blockIdx.x;       // eb*NH + h
    int eb = blk >> 2, h = blk & 3;
    int b = eb >> 3;
    int lane = threadIdx.x;     // 0..63
    int hch = h * HDn + lane;   // channel for this lane (as k-row or v-col)

    __shared__ __align__(16) float kk_s[HDn];
    __shared__ __align__(16) float ew_s[HDn];
    __shared__ __align__(16) float km_s[HDn];
    __shared__ __align__(16) float ck_s[HDn];

    float S[HDn];
#pragma unroll
    for (int k = 0; k < HDn; ++k) S[k] = 0.f;

    int bt0 = (b * Tln) * Hn + hch;   // + t*H
    int et0 = (eb * Tln) * Hn + hch;

    // prefetch t = 0
    float p_kk = kk_g[bt0], p_ew = ew_g[et0], p_km = km_g[et0], p_ck = ck_g[et0];
    float p_vr = vraw_g[bt0], p_sv = sv_g[bt0], p_vf = v_first[et0];
    float vt_last = 0.f;

    for (int t = 0; t < Tln; ++t) {
        float vt = fmaf(p_vf - p_vr, p_sv, p_vr);
        kk_s[lane] = p_kk;
        ew_s[lane] = p_ew;
        km_s[lane] = p_km;
        ck_s[lane] = p_ck;
        __syncthreads();

        if (t + 1 < Tln) {  // prefetch next step under the compute
            int bti = bt0 + (t + 1) * Hn;
            int eti = et0 + (t + 1) * Hn;
            p_kk = kk_g[bti]; p_ew = ew_g[eti]; p_km = km_g[eti]; p_ck = ck_g[eti];
            p_vr = vraw_g[bti]; p_sv = sv_g[bti]; p_vf = v_first[eti];
        }

        float a0c = 0.f, a1c = 0.f, a2c = 0.f, a3c = 0.f;
#pragma unroll
        for (int k = 0; k < HDn; k += 4) {
            a0c = fmaf(kk_s[k + 0], S[k + 0], a0c);
            a1c = fmaf(kk_s[k + 1], S[k + 1], a1c);
            a2c = fmaf(kk_s[k + 2], S[k + 2], a2c);
            a3c = fmaf(kk_s[k + 3], S[k + 3], a3c);
        }
        float aS = -((a0c + a1c) + (a2c + a3c));

#pragma unroll
        for (int k = 0; k < HDn; ++k) {
            S[k] = fmaf(S[k], ew_s[k], fmaf(km_s[k], vt, ck_s[k] * aS));
        }
        vt_last = vt;
        __syncthreads();
    }

    // ---- final step outputs (t = T-1) ----
    __shared__ __align__(16) float xr_s[Hn];
    __shared__ __align__(16) float xg_s[Hn];
    __shared__ float r_s[HDn];
    __shared__ float hg_s[DGn];

    int btl = (b * Tln + (Tln - 1)) * Hn;
#pragma unroll
    for (int i = lane; i < Hn; i += HDn) {
        float hs = keyval[btl + i];
        float q = query[eb * Hn + i];
        float dd = q - hs;
        xr_s[i] = fmaf(dd, x_r[i], hs);
        xg_s[i] = fmaf(dd, x_g[i], hs);
    }
    __syncthreads();

    // r for k-channel hch
    float racc = 0.f;
    {
        const float4* xr4 = (const float4*)xr_s;
        const float4* wr4 = (const float4*)(Wr + hch * Hn);
#pragma unroll 8
        for (int j = 0; j < Hn / 4; ++j) {
            float4 xa = xr4[j], wa = wr4[j];
            racc += xa.x * wa.x + xa.y * wa.y + xa.z * wa.z + xa.w * wa.w;
        }
    }
    r_s[lane] = racc;

    // hg[d] = sigmoid(xg @ g1), lane = d (64 dims)
    float gacc = 0.f;
#pragma unroll 8
    for (int j = 0; j < Hn; ++j) gacc = fmaf(xg_s[j], g1[j * DGn + lane], gacc);
    hg_s[lane] = sigm(gacc);
    __syncthreads();

    // o[v=lane] = sum_k r[k] * S[k][v]
    float o = 0.f;
#pragma unroll
    for (int k = 0; k < HDn; ++k) o = fmaf(r_s[k], S[k], o);

    // groupnorm over the 64 v-lanes
    float mu = wsum64(o) * (1.0f / HDn);
    float dev = o - mu;
    float var = wsum64(dev * dev) * (1.0f / HDn);
    float og = dev * rsqrtf(var + EPSC) * gn_w[hch] + gn_b[hch];

    // rk bonus: s_h = sum_k r[k]*km[k]*r_k[h,k]  (km_s still holds t=T-1 values)
    float part = wsum64(r_s[lane] * km_s[lane] * r_k[hch]);
    float o2 = fmaf(part, vt_last, og);

    // g at channel hch
    float gv = 0.f;
#pragma unroll 8
    for (int dd2 = 0; dd2 < DGn; ++dd2) gv = fmaf(hg_s[dd2], g2[dd2 * Hn + hch], gv);

    o_buf[eb * Hn + hch] = o2 * gv;
}

// ---------------- Kernel D: out = o_buf @ Wo.T ----------------
__global__ void kD(const float* __restrict__ o_buf, const float* __restrict__ Wo,
                   float* __restrict__ out) {
    int eb = blockIdx.x;
    int i = threadIdx.x;
    __shared__ __align__(16) float o_s[Hn];
    o_s[i] = o_buf[eb * Hn + i];
    __syncthreads();
    float acc = 0.f;
    const float4* o4 = (const float4*)o_s;
    const float4* w4 = (const float4*)(Wo + i * Hn);
#pragma unroll 8
    for (int j = 0; j < Hn / 4; ++j) {
        float4 xa = o4[j], wa = w4[j];
        acc += xa.x * wa.x + xa.y * wa.y + xa.z * wa.z + xa.w * wa.w;
    }
    out[eb * Hn + i] = acc;
}

extern "C" void kernel_launch(void* const* d_in, const int* in_sizes, int n_in,
                              void* d_out, int out_size, void* d_ws, size_t ws_size,
                              hipStream_t stream) {
    const float* query  = (const float*)d_in[0];
    const float* keyval = (const float*)d_in[1];
    const float* v_first= (const float*)d_in[2];
    const float* x_r = (const float*)d_in[3];
    const float* x_w = (const float*)d_in[4];
    const float* x_k = (const float*)d_in[5];
    const float* x_v = (const float*)d_in[6];
    const float* x_a = (const float*)d_in[7];
    const float* x_g = (const float*)d_in[8];
    const float* w0  = (const float*)d_in[9];
    const float* w1  = (const float*)d_in[10];
    const float* w2  = (const float*)d_in[11];
    const float* a0  = (const float*)d_in[12];
    const float* a1  = (const float*)d_in[13];
    const float* a2  = (const float*)d_in[14];
    const float* v0  = (const float*)d_in[15];
    const float* v1  = (const float*)d_in[16];
    const float* v2  = (const float*)d_in[17];
    const float* g1  = (const float*)d_in[18];
    const float* g2  = (const float*)d_in[19];
    const float* k_k = (const float*)d_in[20];
    const float* k_a = (const float*)d_in[21];
    const float* r_k = (const float*)d_in[22];
    const float* Wr  = (const float*)d_in[23];
    const float* Wk  = (const float*)d_in[24];
    const float* Wv  = (const float*)d_in[25];
    const float* Wo  = (const float*)d_in[26];
    const float* gn_w= (const float*)d_in[27];
    const float* gn_b= (const float*)d_in[28];

    float* ws = (float*)d_ws;
    const size_t BTH = (size_t)Bqn * Tln * Hn;     // 262144
    const size_t ETH = (size_t)EBn * Tln * Hn;     // 2097152
    float* k_g    = ws;
    float* kk_g   = ws + BTH;
    float* vraw_g = ws + 2 * BTH;
    float* sv_g   = ws + 3 * BTH;
    float* ew_g   = ws + 4 * BTH;
    float* km_g   = ws + 4 * BTH + ETH;
    float* ck_g   = ws + 4 * BTH + 2 * ETH;
    float* o_buf  = ws + 4 * BTH + 3 * ETH;

    kA<<<Bqn * Tln, Hn, 0, stream>>>(keyval, x_k, x_v, Wk, Wv, v0, v1, v2, k_k,
                                     k_g, kk_g, vraw_g, sv_g);
    kB<<<EBn * Tln, Hn, 0, stream>>>(query, keyval, x_w, x_a, w0, w1, w2, a0, a1, a2,
                                     k_a, k_g, kk_g, ew_g, km_g, ck_g);
    kScan<<<EBn * NHn, HDn, 0, stream>>>(kk_g, ew_g, km_g, ck_g, vraw_g, sv_g, v_first,
                                         query, keyval, x_r, x_g, Wr, g1, g2, r_k,
                                         gn_w, gn_b, o_buf);
    kD<<<EBn, Hn, 0, stream>>>(o_buf, Wo, (float*)d_out);
}